// Round 2
// baseline (1029.220 us; speedup 1.0000x reference)
//
#include <hip/hip_runtime.h>

#define N_NODES 100000
#define N_EDGES 1600000

typedef __bf16 bf16x8 __attribute__((ext_vector_type(8)));
typedef float f32x4 __attribute__((ext_vector_type(4)));

__device__ __forceinline__ __bf16 f2bf(float f) { return (__bf16)f; }

__device__ __forceinline__ bf16x8 cvt8(float4 a, float4 b) {
    bf16x8 r;
    r[0] = f2bf(a.x); r[1] = f2bf(a.y); r[2] = f2bf(a.z); r[3] = f2bf(a.w);
    r[4] = f2bf(b.x); r[5] = f2bf(b.y); r[6] = f2bf(b.z); r[7] = f2bf(b.w);
    return r;
}

// ---------------------------------------------------------------------------
// CSR build: deg histogram -> 2-level exclusive scan -> fill (perm + permuted src)
// ---------------------------------------------------------------------------
__global__ __launch_bounds__(256) void k_deg(const int* __restrict__ dst,
                                             int* __restrict__ deg) {
    int e = blockIdx.x * 256 + threadIdx.x;  // exact: E = 6250*256
    atomicAdd(&deg[dst[e]], 1);
}

__global__ __launch_bounds__(256) void k_scanA(const int* __restrict__ deg,
                                               int* __restrict__ bsum) {
    __shared__ int sh[256];
    const int tid = threadIdx.x;
    int n = blockIdx.x * 256 + tid;
    sh[tid] = (n < N_NODES) ? deg[n] : 0;
    __syncthreads();
#pragma unroll
    for (int s = 128; s > 0; s >>= 1) {
        if (tid < s) sh[tid] += sh[tid + s];
        __syncthreads();
    }
    if (tid == 0) bsum[blockIdx.x] = sh[0];
}

#define NB_SCAN 391  // ceil(100000/256)

__global__ __launch_bounds__(512) void k_scanB(const int* __restrict__ bsum,
                                               int* __restrict__ bpre,
                                               int* __restrict__ row_start) {
    __shared__ int sh[512];
    const int tid = threadIdx.x;
    int v = (tid < NB_SCAN) ? bsum[tid] : 0;
    sh[tid] = v;
    __syncthreads();
#pragma unroll
    for (int off = 1; off < 512; off <<= 1) {
        int t = (tid >= off) ? sh[tid - off] : 0;
        __syncthreads();
        sh[tid] += t;
        __syncthreads();
    }
    if (tid < NB_SCAN) bpre[tid] = sh[tid] - v;  // exclusive
    if (tid == 0) row_start[N_NODES] = N_EDGES;
}

__global__ __launch_bounds__(256) void k_scanC(const int* __restrict__ deg,
                                               const int* __restrict__ bpre,
                                               int* __restrict__ row_start,
                                               int* __restrict__ cursor) {
    __shared__ int sh[256];
    const int tid = threadIdx.x;
    int n = blockIdx.x * 256 + tid;
    int v = (n < N_NODES) ? deg[n] : 0;
    sh[tid] = v;
    __syncthreads();
#pragma unroll
    for (int off = 1; off < 256; off <<= 1) {
        int t = (tid >= off) ? sh[tid - off] : 0;
        __syncthreads();
        sh[tid] += t;
        __syncthreads();
    }
    if (n < N_NODES) {
        int ex = sh[tid] - v + bpre[blockIdx.x];
        row_start[n] = ex;
        cursor[n]    = ex;
    }
}

__global__ __launch_bounds__(256) void k_fill(const int* __restrict__ src,
                                              const int* __restrict__ dst,
                                              int* __restrict__ cursor,
                                              int* __restrict__ perm,
                                              int* __restrict__ srcp) {
    int e = blockIdx.x * 256 + threadIdx.x;  // exact
    int d = dst[e];
    int pos = atomicAdd(&cursor[d], 1);
    perm[e] = pos;
    srcp[pos] = src[e];
}

// ---------------------------------------------------------------------------
// K1: node GEMMs (unchanged). Wave w of 3 handles one of W_ni/W_nj/W_src.
// ---------------------------------------------------------------------------
__global__ __launch_bounds__(192) void k_node(
    const float* __restrict__ nfeats,
    const float* __restrict__ Wni, const float* __restrict__ Wnj,
    const float* __restrict__ Wsrc, const float* __restrict__ bsrc,
    float* __restrict__ fni, float* __restrict__ fnj, float* __restrict__ hsrc) {
    const int wid  = threadIdx.x >> 6;
    const int lane = threadIdx.x & 63;
    const int quad = lane >> 4, n = lane & 15;

    const float* W  = (wid == 0) ? Wni : (wid == 1) ? Wnj : Wsrc;
    float*       out = (wid == 0) ? fni : (wid == 1) ? fnj : hsrc;

    bf16x8 Bf[4][4];
#pragma unroll
    for (int t = 0; t < 4; ++t)
#pragma unroll
        for (int kc = 0; kc < 4; ++kc)
#pragma unroll
            for (int j = 0; j < 8; ++j) {
                int k = kc * 32 + quad * 8 + j;
                Bf[t][kc][j] = f2bf(W[k * 64 + t * 16 + n]);
            }
    float bs[4];
#pragma unroll
    for (int t = 0; t < 4; ++t) bs[t] = (wid == 2) ? bsrc[t * 16 + n] : 0.0f;

    for (int chunk = blockIdx.x; chunk < N_NODES / 16; chunk += gridDim.x) {
        const int n0 = chunk * 16;
        const float* ap = nfeats + (n0 + n) * 128 + quad * 8;
        bf16x8 Af[4];
#pragma unroll
        for (int kc = 0; kc < 4; ++kc) {
            float4 a0 = *(const float4*)(ap + kc * 32);
            float4 a1 = *(const float4*)(ap + kc * 32 + 4);
            Af[kc] = cvt8(a0, a1);
        }
#pragma unroll
        for (int t = 0; t < 4; ++t) {
            f32x4 acc = {0.f, 0.f, 0.f, 0.f};
#pragma unroll
            for (int kc = 0; kc < 4; ++kc)
                acc = __builtin_amdgcn_mfma_f32_16x16x32_bf16(Af[kc], Bf[t][kc], acc, 0, 0, 0);
#pragma unroll
            for (int reg = 0; reg < 4; ++reg) {
                int row = quad * 4 + reg;
                out[(n0 + row) * 64 + t * 16 + n] = acc[reg] + bs[t];
            }
        }
    }
}

// ---------------------------------------------------------------------------
// K2: fused edge pass. MFMA f_fij + gathers + leaky + res_e + logits + exp.
// exp written PERMUTED into CSR slot order (perm[e]); no z atomics.
// ---------------------------------------------------------------------------
__global__ __launch_bounds__(256) void k_edge1(
    const float* __restrict__ efeats,
    const int* __restrict__ src, const int* __restrict__ dst,
    const float* __restrict__ Wf, const float* __restrict__ biasE,
    const float* __restrict__ attn,
    const float* __restrict__ fni, const float* __restrict__ fnj,
    const int* __restrict__ perm,
    float* __restrict__ rese, float* __restrict__ exw) {
    __shared__ float shF[4][16][68];  // per-wave private [16 edges][64+pad]
    const int wid  = threadIdx.x >> 6;
    const int lane = threadIdx.x & 63;
    const int quad = lane >> 4, dcol = lane & 15;

    bf16x8 Bf[4][2];
#pragma unroll
    for (int t = 0; t < 4; ++t)
#pragma unroll
        for (int q = 0; q < 2; ++q)
#pragma unroll
            for (int j = 0; j < 8; ++j) {
                int k = q * 32 + quad * 8 + j;
                Bf[t][q][j] = f2bf(Wf[k * 64 + t * 16 + dcol]);
            }
    float bias_r[4];
#pragma unroll
    for (int h = 0; h < 4; ++h) bias_r[h] = biasE[h * 16 + dcol];

    const int h4 = lane & 3, el = lane >> 2;  // logit-stage roles
    float atr[16];
#pragma unroll
    for (int i = 0; i < 16; ++i) atr[i] = attn[h4 * 16 + i];

    const int nchunk = N_EDGES / 16;
    const int wgid = blockIdx.x * 4 + wid;
    const int nw   = gridDim.x * 4;
    for (int chunk = wgid; chunk < nchunk; chunk += nw) {
        const int e0 = chunk * 16;
        const float* ap = efeats + (e0 + dcol) * 64 + quad * 8;
        bf16x8 af0 = cvt8(*(const float4*)ap, *(const float4*)(ap + 4));
        bf16x8 af1 = cvt8(*(const float4*)(ap + 32), *(const float4*)(ap + 36));
        f32x4 acc[4];
#pragma unroll
        for (int t = 0; t < 4; ++t) {
            f32x4 c0 = {0.f, 0.f, 0.f, 0.f};
            c0     = __builtin_amdgcn_mfma_f32_16x16x32_bf16(af0, Bf[t][0], c0, 0, 0, 0);
            acc[t] = __builtin_amdgcn_mfma_f32_16x16x32_bf16(af1, Bf[t][1], c0, 0, 0, 0);
        }
#pragma unroll
        for (int reg = 0; reg < 4; ++reg) {
            const int row = quad * 4 + reg;
            const int er  = e0 + row;
            const int s = src[er], dd = dst[er];
            const float* pni = fni + s * 64 + dcol;
            const float* pnj = fnj + dd * 64 + dcol;
            float re = 0.f;
#pragma unroll
            for (int h = 0; h < 4; ++h) {
                float v = acc[h][reg] + pni[h * 16] + pnj[h * 16] + bias_r[h];
                v = (v > 0.f) ? v : 0.01f * v;
                re += v;
                shF[wid][row][h * 16 + dcol] = v;
            }
            rese[er * 16 + dcol] = 0.25f * re;
        }
        // logits: lane covers (edge el, head h4); wave-private LDS, no barrier
        const float* pf = &shF[wid][el][h4 * 16];
        float4 b0 = *(const float4*)pf;
        float4 b1 = *(const float4*)(pf + 4);
        float4 b2 = *(const float4*)(pf + 8);
        float4 b3 = *(const float4*)(pf + 12);
        float eh = b0.x * atr[0]  + b0.y * atr[1]  + b0.z * atr[2]  + b0.w * atr[3]
                 + b1.x * atr[4]  + b1.y * atr[5]  + b1.z * atr[6]  + b1.w * atr[7]
                 + b2.x * atr[8]  + b2.y * atr[9]  + b2.z * atr[10] + b2.w * atr[11]
                 + b3.x * atr[12] + b3.y * atr[13] + b3.z * atr[14] + b3.w * atr[15];
        float exv = __expf(eh);
        int p = perm[e0 + el];
        exw[p * 4 + h4] = exv;   // scattered 16B store into CSR order
    }
}

// ---------------------------------------------------------------------------
// K3 (pull): one wave per node, lane=(h,d). Sequential CSR edge loop:
// exw/srcp contiguous, hsrc row gather coalesced 256B. Zero atomics.
// ---------------------------------------------------------------------------
__global__ __launch_bounds__(256) void k_pull(
    const int* __restrict__ row_start, const int* __restrict__ srcp,
    const float* __restrict__ exw, const float* __restrict__ hsrc,
    float* __restrict__ resn) {
    const int wid  = threadIdx.x >> 6;
    const int lane = threadIdx.x & 63;
    const int h = lane >> 4;
    const int n = blockIdx.x * 4 + wid;   // exact: 25000*4 = N_NODES
    const int start = row_start[n], end = row_start[n + 1];
    float sacc = 0.f, zacc = 0.f;
    int i = start;
    for (; i + 2 <= end; i += 2) {        // 2 hsrc loads in flight
        int sn0 = srcp[i], sn1 = srcp[i + 1];
        float ex0 = exw[i * 4 + h], ex1 = exw[i * 4 + 4 + h];
        float v0 = hsrc[sn0 * 64 + lane], v1 = hsrc[sn1 * 64 + lane];
        sacc += ex0 * v0 + ex1 * v1;
        zacc += ex0 + ex1;
    }
    if (i < end) {
        int sn0 = srcp[i];
        float ex0 = exw[i * 4 + h];
        sacc += ex0 * hsrc[sn0 * 64 + lane];
        zacc += ex0;
    }
    float v = (end > start) ? sacc * __builtin_amdgcn_rcpf(zacc) : 0.f;
    v += __shfl_xor(v, 16, 64);
    v += __shfl_xor(v, 32, 64);
    if (lane < 16) resn[n * 16 + lane] = 0.25f * v;
}

extern "C" void kernel_launch(void* const* d_in, const int* in_sizes, int n_in,
                              void* d_out, int out_size, void* d_ws, size_t ws_size,
                              hipStream_t stream) {
    const float* nfeats = (const float*)d_in[0];
    const float* efeats = (const float*)d_in[1];
    const int*   src    = (const int*)d_in[2];
    const int*   dst    = (const int*)d_in[3];
    const float* W_ni   = (const float*)d_in[4];
    const float* W_nj   = (const float*)d_in[5];
    const float* W_fij  = (const float*)d_in[6];
    const float* W_src  = (const float*)d_in[7];
    const float* b_src  = (const float*)d_in[8];
    const float* attn   = (const float*)d_in[9];
    const float* bias_e = (const float*)d_in[10];

    float* resn = (float*)d_out;                       // [N, 16]
    float* rese = resn + (size_t)N_NODES * 16;         // [E, 16]

    float* ws   = (float*)d_ws;
    float* fni  = ws;                                  // [N, 64]
    float* fnj  = fni  + (size_t)N_NODES * 64;         // [N, 64]
    float* hsrc = fnj  + (size_t)N_NODES * 64;         // [N, 64]
    float* exw  = hsrc + (size_t)N_NODES * 64;         // [E, 4] CSR-ordered
    int*   iws  = (int*)(exw + (size_t)N_EDGES * 4);
    int* deg       = iws;                              // [N]
    int* cursor    = deg + N_NODES;                    // [N]
    int* row_start = cursor + N_NODES;                 // [N+1]
    int* perm      = row_start + N_NODES + 1;          // [E]
    int* srcp      = perm + N_EDGES;                   // [E]
    int* bsum      = srcp + N_EDGES;                   // [NB_SCAN]
    int* bpre      = bsum + NB_SCAN;                   // [NB_SCAN]

    hipMemsetAsync(deg, 0, (size_t)N_NODES * sizeof(int), stream);

    k_deg  <<<N_EDGES / 256, 256, 0, stream>>>(dst, deg);
    k_scanA<<<NB_SCAN, 256, 0, stream>>>(deg, bsum);
    k_scanB<<<1, 512, 0, stream>>>(bsum, bpre, row_start);
    k_scanC<<<NB_SCAN, 256, 0, stream>>>(deg, bpre, row_start, cursor);
    k_fill <<<N_EDGES / 256, 256, 0, stream>>>(src, dst, cursor, perm, srcp);

    k_node <<<1024, 192, 0, stream>>>(nfeats, W_ni, W_nj, W_src, b_src, fni, fnj, hsrc);
    k_edge1<<<4096, 256, 0, stream>>>(efeats, src, dst, W_fij, bias_e, attn,
                                      fni, fnj, perm, rese, exw);
    k_pull <<<N_NODES / 4, 256, 0, stream>>>(row_start, srcp, exw, hsrc, resn);
}